// Round 12
// baseline (1985.384 us; speedup 1.0000x reference)
//
#include <hip/hip_runtime.h>
#include <hip/hip_bf16.h>
#include <stdint.h>

#define BSZ 1024
#define HSZ 512
#define TSZ 48
#define INSZ 64
#define GSZ 2048  // 4*HSZ

typedef __attribute__((ext_vector_type(8))) short bf16x8;
typedef __attribute__((ext_vector_type(16))) float f32x16;

#define GLDS16(g, l)                                                        \
    __builtin_amdgcn_global_load_lds(                                       \
        (const __attribute__((address_space(1))) void*)(g),                 \
        (__attribute__((address_space(3))) void*)(l), 16, 0, 0)

#define SB0 __builtin_amdgcn_sched_barrier(0);
#define WAITV8 asm volatile("s_waitcnt vmcnt(8)" ::: "memory");
#define BARRAW __builtin_amdgcn_s_barrier();

__device__ __forceinline__ float sigmf(float x) { return 1.0f / (1.0f + __expf(-x)); }
__device__ __forceinline__ float tanhf_(float x) { return 2.0f / (1.0f + __expf(-2.0f * x)) - 1.0f; }

// Layouts (bf16, hi/lo separate slabs):
//   A slabs: [p=row/64][kc=hid/8][r=row&63][e=hid&7]
//   W slabs: [np=col'/128][kc=k/8][c=col'&127][e=k&7], col' = hidden*4+gate
// r11 -> r12: replace __syncthreads (vmcnt(0) drain, ~300-700cy exposed/kstep)
// with T4 counted waits + raw barrier:
//   iter ks: stage(ks+1) [4 glds, OLDEST] | LOADB(ks+1) [8 loads] |
//            COMPUTE(ks) [B regs compiler-counted, never 0] |
//            s_waitcnt vmcnt(8) [completes glds only] | s_barrier
// sched_barrier(0) pins each region so the glds stay oldest in the queue.
// B register double-buffer (bA/bB named sets, even/odd unroll; rule #20).
// Wave tile 64x32; MFMA 32x32x16; 3-product hi/lo split.
// grid (16,16,ncells): 64 rows x 128 gate-cols per block, 256 threads.
__global__ __launch_bounds__(256, 3) void lstm_diag(
    const __hip_bfloat16* __restrict__ xth, const __hip_bfloat16* __restrict__ xtl,
    __hip_bfloat16* __restrict__ hbuf,   // [par][layer][hilo] pk-slabs
    float* __restrict__ Cbuf,            // [layer][B*H] linear f32
    const __hip_bfloat16* __restrict__ W0h, const __hip_bfloat16* __restrict__ W0l,
    const __hip_bfloat16* __restrict__ W1h, const __hip_bfloat16* __restrict__ W1l,
    const __hip_bfloat16* __restrict__ W2h, const __hip_bfloat16* __restrict__ W2l,
    const float* __restrict__ b0, const float* __restrict__ b1,
    const float* __restrict__ b2,
    int d, int lmin)
{
    // A dbuf: 2 x (hi 8K | lo 8K) = 32K; epilogue gt 64*132*4 = 33792 (aliased)
    __shared__ __align__(16) char lds[33792];

    const int l = lmin + blockIdx.z;
    const int t = d - l;
    const size_t slab = (size_t)BSZ * HSZ;
    auto Hb = [&](int par, int ll, int hilo) {
        return hbuf + (((size_t)par * 3 + ll) * 2 + hilo) * slab;
    };

    const __hip_bfloat16* Wth = (l == 0) ? W0h : (l == 1) ? W1h : W2h;
    const __hip_bfloat16* Wtl = (l == 0) ? W0l : (l == 1) ? W1l : W2l;
    const float* bias = (l == 0) ? b0 : (l == 1) ? b1 : b2;
    const int Kx   = (l == 0) ? INSZ : HSZ;
    const int KCax = (l == 0) ? 8 : 64;   // kcs per panel in the x-source slab
    const int Ktot = Kx + HSZ;
    const int KCt  = Ktot >> 3;
    const int nkx  = Kx >> 6;     // ksteps in x phase (1 or 8)
    const int nkt  = Ktot >> 6;   // total ksteps (9 or 16)
    const int cur = t & 1, prv = cur ^ 1;
    const __hip_bfloat16* Axh = (l == 0) ? xth + (size_t)t * BSZ * INSZ : Hb(cur, l - 1, 0);
    const __hip_bfloat16* Axl = (l == 0) ? xtl + (size_t)t * BSZ * INSZ : Hb(cur, l - 1, 1);
    const __hip_bfloat16* Ahh = Hb(prv, l, 0);
    const __hip_bfloat16* Ahl = Hb(prv, l, 1);
    float* C = Cbuf + (size_t)l * slab;
    __hip_bfloat16* hhi = Hb(cur, l, 0);
    __hip_bfloat16* hlo = Hb(cur, l, 1);

    // XCD-aware bijective swizzle within the 256-block z-slice (256 % 8 == 0).
    const int bid = blockIdx.x + (blockIdx.y << 4);
    const int swz = (bid & 7) * 32 + (bid >> 3);
    const int m0 = (swz & 15) * 64;
    const int n0 = (swz >> 4) * 128;
    const int p  = swz & 15;    // A row-panel
    const int np = swz >> 4;    // W col-panel

    const int tid = threadIdx.x;
    const int lane = tid & 63;
    const int wv = tid >> 6;
    const int lrow32 = lane & 31;
    const int lk2 = lane >> 5;

    // A source byte bases (panel-resolved)
    const char* bAxh = (const char*)Axh + (size_t)p * KCax * 1024;
    const char* bAxl = (const char*)Axl + (size_t)p * KCax * 1024;
    const char* bAhh = (const char*)Ahh + (size_t)p * 64 * 1024;
    const char* bAhl = (const char*)Ahl + (size_t)p * 64 * 1024;
    // W byte bases (panel-resolved)
    const char* bWh = (const char*)Wth + (size_t)np * KCt * 2048;
    const char* bWl = (const char*)Wtl + (size_t)np * KCt * 2048;

    // per-lane offsets: wave owns cols [wv*32, wv*32+32) of the 128-col block
    const int boff = (wv * 32 + lrow32) * 16;   // + kc*2048
    const int aoff = lrow32 * 16;               // + kc*1024 (+512 for rows 32-63)

    f32x16 acc0, acc1;
#pragma unroll
    for (int r = 0; r < 16; ++r) { acc0[r] = 0.0f; acc1[r] = 0.0f; }

    // stage A kstep ks into buf[ks&1]: 16 x 1KB segments, 4 per wave
    auto stage = [&](int ks) {
        const char *sh, *sl;
        int kc0;
        if (ks < nkx) { sh = bAxh; sl = bAxl; kc0 = ks * 8; }
        else          { sh = bAhh; sl = bAhl; kc0 = (ks - nkx) * 8; }
        char* dst = lds + (ks & 1) * 16384;
#pragma unroll
        for (int i = 0; i < 2; ++i) {
            int kc = wv * 2 + i;
            size_t so = (size_t)(kc0 + kc) * 1024 + lane * 16;
            GLDS16(sh + so, dst + kc * 1024);
            GLDS16(sl + so, dst + 8192 + kc * 1024);
        }
    };

    bf16x8 bA[8], bB[8];   // [0..3]=hi per ksub, [4..7]=lo per ksub

#define LOADB(SET, KS)                                                      \
    { const char* wb_ = bWh + (size_t)(KS) * 16384;                         \
      const char* wl_ = bWl + (size_t)(KS) * 16384;                         \
      _Pragma("unroll")                                                     \
      for (int s_ = 0; s_ < 4; ++s_) {                                      \
          int ko_ = (s_ * 2 + lk2) * 2048 + boff;                           \
          SET[s_]     = *(const bf16x8*)(wb_ + ko_);                        \
          SET[s_ + 4] = *(const bf16x8*)(wl_ + ko_);                        \
      } }

#define COMPUTE(SET, KS)                                                    \
    { char* buf_ = lds + ((KS) & 1) * 16384;                                \
      __builtin_amdgcn_s_setprio(1);                                        \
      _Pragma("unroll")                                                     \
      for (int s_ = 0; s_ < 4; ++s_) {                                      \
          int ao_ = (s_ * 2 + lk2) * 1024 + aoff;                           \
          bf16x8 ah0 = *(const bf16x8*)(buf_ + ao_);                        \
          bf16x8 ah1 = *(const bf16x8*)(buf_ + ao_ + 512);                  \
          bf16x8 al0 = *(const bf16x8*)(buf_ + 8192 + ao_);                 \
          bf16x8 al1 = *(const bf16x8*)(buf_ + 8192 + ao_ + 512);           \
          acc0 = __builtin_amdgcn_mfma_f32_32x32x16_bf16(ah0, SET[s_], acc0, 0, 0, 0);     \
          acc1 = __builtin_amdgcn_mfma_f32_32x32x16_bf16(ah1, SET[s_], acc1, 0, 0, 0);     \
          acc0 = __builtin_amdgcn_mfma_f32_32x32x16_bf16(al0, SET[s_], acc0, 0, 0, 0);     \
          acc1 = __builtin_amdgcn_mfma_f32_32x32x16_bf16(al1, SET[s_], acc1, 0, 0, 0);     \
          acc0 = __builtin_amdgcn_mfma_f32_32x32x16_bf16(ah0, SET[s_ + 4], acc0, 0, 0, 0); \
          acc1 = __builtin_amdgcn_mfma_f32_32x32x16_bf16(ah1, SET[s_ + 4], acc1, 0, 0, 0); \
      }                                                                     \
      __builtin_amdgcn_s_setprio(0); }

    // prologue: glds(0) oldest, then B[0]; vmcnt(8) completes glds(0) only;
    // barrier publishes buf0 to all waves. B[0] stays in flight.
    stage(0);
    SB0
    LOADB(bA, 0)
    SB0
    WAITV8
    BARRAW

#pragma unroll 1
    for (int ks = 0; ks < nkt; ) {
        // even step: consume bA; prefetch glds(ks+1) then B[ks+1] into bB
        if (ks + 1 < nkt) { stage(ks + 1); SB0 LOADB(bB, ks + 1) }
        SB0
        COMPUTE(bA, ks)
        SB0
        WAITV8          // glds(ks+1) done; 8 B[ks+1] remain in flight
        BARRAW          // buf[(ks+1)&1] published; WAR for next overwrite
        ++ks;
        if (ks == nkt) break;
        // odd step: consume bB; prefetch into bA
        if (ks + 1 < nkt) { stage(ks + 1); SB0 LOADB(bA, ks + 1) }
        SB0
        COMPUTE(bB, ks)
        SB0
        WAITV8
        BARRAW
        ++ks;
    }
#undef LOADB
#undef COMPUTE
    SB0

    // ---- epilogue: acc -> LDS [64][132] f32, then fused cell update ----
    // (loop's final barrier already synced; gt aliases the A bufs)
    float* gt = (float*)lds;
#pragma unroll
    for (int rg = 0; rg < 16; ++rg) {
        int row = (rg & 3) + 8 * (rg >> 2) + 4 * lk2;
        gt[row * 132 + wv * 32 + lrow32] = acc0[rg];
        gt[(row + 32) * 132 + wv * 32 + lrow32] = acc1[rg];
    }
    __syncthreads();

    const int n_l = tid & 31;
    const int rb2 = (tid >> 5) * 8;
    const int n_g = (n0 >> 2) + n_l;  // global hidden unit
    const int kc_h = n_g >> 3, e_h = n_g & 7;
    const float bf = bias[n_g], bi = bias[HSZ + n_g];
    const float bc = bias[2 * HSZ + n_g], bo = bias[3 * HSZ + n_g];
#pragma unroll
    for (int r = 0; r < 8; ++r) {
        int row = rb2 + r;
        int rg = m0 + row;
        float4 g4 = *(const float4*)&gt[row * 132 + n_l * 4];  // f,i,c,o
        float f = sigmf(g4.x + bf);
        float i_ = sigmf(g4.y + bi);
        float c_ = tanhf_(g4.z + bc);
        float o_ = sigmf(g4.w + bo);
        size_t cidx = (size_t)rg * HSZ + n_g;
        float Cn = f * C[cidx] + i_ * c_;
        C[cidx] = Cn;
        float hv = o_ * tanhf_(Cn);
        __hip_bfloat16 hh = __float2bfloat16(hv);
        size_t hidx = (((size_t)(rg >> 6) * 64 + kc_h) * 64 + (rg & 63)) * 8 + e_h;
        hhi[hidx] = hh;
        hlo[hidx] = __float2bfloat16(hv - __bfloat162float(hh));
    }
}

// x[B][T][64] f32 -> xt_pk[t][p][kc][r][e] bf16 hi/lo
__global__ __launch_bounds__(256) void convert_x(const float* __restrict__ x,
                                                 __hip_bfloat16* __restrict__ xh,
                                                 __hip_bfloat16* __restrict__ xl)
{
    int gid = blockIdx.x * 256 + threadIdx.x;  // T*16*64*8
    int kc = gid & 7;
    int rem = gid >> 3;
    int r = rem & 63; rem >>= 6;
    int pp = rem & 15;
    int t = rem >> 4;
    int b = pp * 64 + r;
    const float* src = x + ((size_t)b * TSZ + t) * INSZ + kc * 8;
    short hi8[8], lo8[8];
#pragma unroll
    for (int e = 0; e < 8; ++e) {
        float v = src[e];
        __hip_bfloat16 h = __float2bfloat16(v);
        hi8[e] = *(short*)&h;
        __hip_bfloat16 lo = __float2bfloat16(v - __bfloat162float(h));
        lo8[e] = *(short*)&lo;
    }
    size_t o = ((((size_t)t * 16 + pp) * 8 + kc) * 64 + r) * 8;
    *(bf16x8*)((__hip_bfloat16*)xh + o) = *(bf16x8*)hi8;
    *(bf16x8*)((__hip_bfloat16*)xl + o) = *(bf16x8*)lo8;
}

// W[k][gate*512+n] f32 (Wx then Wh stacked in k) -> W_pk[np][kc][c][e] bf16 hi/lo
// grid (Ktot/64, 16): block = (kt, np), 64 k x 128 col'
__global__ __launch_bounds__(256) void convert_w(
    const float* __restrict__ Wx, const float* __restrict__ Wh, int Kx, int Ktot,
    __hip_bfloat16* __restrict__ outh, __hip_bfloat16* __restrict__ outl)
{
    __shared__ float tile[64][129];
    const int kt = blockIdx.x, np = blockIdx.y;
    const int k0 = kt * 64;
    const float* src;
    int krel;
    if (k0 < Kx) { src = Wx; krel = k0; } else { src = Wh; krel = k0 - Kx; }
#pragma unroll
    for (int i = 0; i < 32; ++i) {
        int idx = threadIdx.x + i * 256;
        int k_l = idx >> 7, gate = (idx >> 5) & 3, n_l = idx & 31;
        tile[k_l][n_l * 4 + gate] = src[(size_t)(krel + k_l) * GSZ + gate * HSZ + np * 32 + n_l];
    }
    __syncthreads();
    const size_t obase = ((size_t)np * (Ktot >> 3) + kt * 8) * 1024;
#pragma unroll
    for (int i = 0; i < 32; ++i) {
        int idx = threadIdx.x + i * 256;
        int kcl = idx >> 10, c = (idx >> 3) & 127, e = idx & 7;
        float v = tile[kcl * 8 + e][c];
        __hip_bfloat16 h = __float2bfloat16(v);
        outh[obase + idx] = h;
        outl[obase + idx] = __float2bfloat16(v - __bfloat162float(h));
    }
}

// out[b] = sum_n (hh+hl)[b][n]*w[n] + bias, h in pk layout
__global__ __launch_bounds__(256) void fc_kernel(
    const __hip_bfloat16* __restrict__ hh, const __hip_bfloat16* __restrict__ hl,
    const float* __restrict__ w, const float* __restrict__ b, float* __restrict__ out)
{
    int wave = (blockIdx.x * 256 + threadIdx.x) >> 6;  // batch row
    int lane = threadIdx.x & 63;
    if (wave >= BSZ) return;
    int pp = wave >> 6, r = wave & 63;
    size_t o = (((size_t)pp * 64 + lane) * 64 + r) * 8;  // kc = lane
    bf16x8 vh = *(const bf16x8*)(hh + o);
    bf16x8 vl = *(const bf16x8*)(hl + o);
    float s = 0.0f;
#pragma unroll
    for (int e = 0; e < 8; ++e) {
        ushort uh = (ushort)vh[e], ul = (ushort)vl[e];
        __hip_bfloat16 bh = *(__hip_bfloat16*)&uh;
        __hip_bfloat16 bl = *(__hip_bfloat16*)&ul;
        s += (__bfloat162float(bh) + __bfloat162float(bl)) * w[lane * 8 + e];
    }
#pragma unroll
    for (int off = 32; off; off >>= 1) s += __shfl_down(s, off);
    if (lane == 0) out[wave] = s + b[0];
}

extern "C" void kernel_launch(void* const* d_in, const int* in_sizes, int n_in,
                              void* d_out, int out_size, void* d_ws, size_t ws_size,
                              hipStream_t stream) {
    const float* x   = (const float*)d_in[0];
    const float* Wx0 = (const float*)d_in[1];
    const float* Wh0 = (const float*)d_in[2];
    const float* b0  = (const float*)d_in[3];
    const float* Wx1 = (const float*)d_in[4];
    const float* Wh1 = (const float*)d_in[5];
    const float* b1  = (const float*)d_in[6];
    const float* Wx2 = (const float*)d_in[7];
    const float* Wh2 = (const float*)d_in[8];
    const float* b2  = (const float*)d_in[9];
    const float* fcw = (const float*)d_in[10];
    const float* fcb = (const float*)d_in[11];

    char* p = (char*)d_ws;
    const size_t hslab = (size_t)BSZ * HSZ * sizeof(__hip_bfloat16);  // 1 MiB
    __hip_bfloat16* hbuf = (__hip_bfloat16*)p;  // [par][layer][hi/lo] 12 slabs
    p += 12 * hslab;
    float* Cbuf = (float*)p;  // [3][B][H] f32
    p += 3 * (size_t)BSZ * HSZ * sizeof(float);
    const size_t zero_bytes = (size_t)(p - (char*)d_ws);

    const size_t xslab = (size_t)TSZ * BSZ * INSZ * sizeof(__hip_bfloat16);
    __hip_bfloat16* xth = (__hip_bfloat16*)p; p += xslab;
    __hip_bfloat16* xtl = (__hip_bfloat16*)p; p += xslab;

    const int K0 = INSZ + HSZ;   // 576
    const int K12 = 2 * HSZ;     // 1024
    const size_t w0s = (size_t)GSZ * K0 * sizeof(__hip_bfloat16);
    const size_t w12s = (size_t)GSZ * K12 * sizeof(__hip_bfloat16);
    __hip_bfloat16* w0h = (__hip_bfloat16*)p; p += w0s;
    __hip_bfloat16* w0l = (__hip_bfloat16*)p; p += w0s;
    __hip_bfloat16* w1h = (__hip_bfloat16*)p; p += w12s;
    __hip_bfloat16* w1l = (__hip_bfloat16*)p; p += w12s;
    __hip_bfloat16* w2h = (__hip_bfloat16*)p; p += w12s;
    __hip_bfloat16* w2l = (__hip_bfloat16*)p; p += w12s;

    hipMemsetAsync(d_ws, 0, zero_bytes, stream);

    convert_x<<<dim3(TSZ * BSZ * 8 / 256), dim3(256), 0, stream>>>(x, xth, xtl);
    convert_w<<<dim3(K0 / 64, 16), dim3(256), 0, stream>>>(Wx0, Wh0, INSZ, K0, w0h, w0l);
    convert_w<<<dim3(K12 / 64, 16), dim3(256), 0, stream>>>(Wx1, Wh1, HSZ, K12, w1h, w1l);
    convert_w<<<dim3(K12 / 64, 16), dim3(256), 0, stream>>>(Wx2, Wh2, HSZ, K12, w2h, w2l);

    // diagonal wavefront: d = t + l, cells (t,l) with t+l == d are independent
    for (int dgn = 0; dgn < TSZ + 2; ++dgn) {
        int lmin = (dgn - (TSZ - 1)) > 0 ? (dgn - (TSZ - 1)) : 0;
        int lmax = dgn < 2 ? dgn : 2;
        int ncells = lmax - lmin + 1;
        lstm_diag<<<dim3(16, 16, ncells), dim3(256), 0, stream>>>(
            xth, xtl, hbuf, Cbuf,
            w0h, w0l, w1h, w1l, w2h, w2l,
            b0, b1, b2, dgn, lmin);
    }

    // h of layer 2 at t=47 lives at parity 47&1 = 1
    __hip_bfloat16* h2h = hbuf + (((size_t)1 * 3 + 2) * 2 + 0) * BSZ * HSZ;
    __hip_bfloat16* h2l = hbuf + (((size_t)1 * 3 + 2) * 2 + 1) * BSZ * HSZ;
    fc_kernel<<<dim3(BSZ / 4), dim3(256), 0, stream>>>(h2h, h2l, fcw, fcb, (float*)d_out);
}